// Round 5
// baseline (139.795 us; speedup 1.0000x reference)
//
#include <hip/hip_runtime.h>

// Problem constants (fixed shapes from setup_inputs / PROJECT_CFG)
#define BB   2
#define CC   32
#define NN   8192               // H*W points per batch
#define N2   (2 * NN)           // near rows [0,NN) + far rows [NN,2NN) in F
#define NXv  440
#define NYv  500
#define NVOXv (NXv * NYv)       // 220000

#define SPLIT 16                // lanes per far point
#define FPB   16                // far points per 256-thread block

#define INSERT3(dd, jj)                                            \
    if ((dd) < d2) {                                               \
        if ((dd) < d1) {                                           \
            d2 = d1; i2 = i1;                                      \
            if ((dd) < d0) { d1 = d0; i1 = i0; d0 = (dd); i0 = (jj); } \
            else           { d1 = (dd); i1 = (jj); }               \
        } else { d2 = (dd); i2 = (jj); }                           \
    }

// ---------------------------------------------------------------------------
// Fused: fv (B,C,N) -> F rows [0,NN) as (B,N,C)  +  compact near/far + chain.
// Counters start at -1 (0xFF memset): pos = atomicAdd(c,1)+1, count = c+1.
// ---------------------------------------------------------------------------
__global__ __launch_bounds__(256) void k_prep(
    const float* __restrict__ fv,    // (B,C,N)
    const float* __restrict__ pim,   // (B,4,N)
    const float* __restrict__ pimf,  // (B,4,N)
    const int*   __restrict__ pm,    // (B,N)
    const int*   __restrict__ pmf,   // (B,N)
    float*       __restrict__ F,     // (B,2N,C)
    int*         __restrict__ head,  // (B,NVOX), init -1
    int*         __restrict__ nxt,   // (B,2N)
    float4*      __restrict__ cand,  // (B,N)
    int*         __restrict__ counters, // [ccnt0,ccnt1,fcnt0,fcnt1], init -1
    float4*      __restrict__ fcand) // (B,N)
{
    __shared__ float tile[CC][64 + 1];
    int b  = blockIdx.y;
    int i0 = blockIdx.x * 64;
    int t  = threadIdx.x;

    // ---- transpose 64 points of fv into F rows [0,NN) ----
    const float* f = fv + (size_t)b * CC * NN;
    int il = t & 63, cb = t >> 6;            // cb 0..3
#pragma unroll
    for (int p = 0; p < 8; ++p) {
        int c = cb + p * 4;
        tile[c][il] = f[(size_t)c * NN + i0 + il];
    }
    __syncthreads();
    float* o = F + ((size_t)b * N2 + i0) * CC;
    int c2 = t & 31, ib = t >> 5;            // ib 0..7
#pragma unroll
    for (int p = 0; p < 8; ++p) {
        int il2 = ib + p * 8;
        o[(size_t)il2 * CC + c2] = tile[c2][il2];
    }

    // ---- wave 0: compact + chain the same 64 points ----
    if (t < 64) {
        int i = i0 + t;

        // far point: compact (pmf>0 && in-bounds); store vox in .w
        {
            float x = pimf[(b * 4 + 0) * NN + i];
            float y = pimf[(b * 4 + 1) * NN + i];
            float z = pimf[(b * 4 + 2) * NN + i];
            if (pmf[b * NN + i] > 0) {
                int ix = (int)floorf((x - 0.0f)  / 0.16f);
                int iy = (int)floorf((y + 40.0f) / 0.16f);
                if (ix >= 0 && ix < NXv && iy >= 0 && iy < NYv &&
                    z >= -3.0f && z < 1.0f) {
                    int vox = iy * NXv + ix;
                    int pos = atomicAdd(&counters[2 + b], 1) + 1;
                    fcand[b * NN + pos] = make_float4(x, y, z, __int_as_float(vox));
                }
            }
        }

        // near point: candidate list (mask only) + chain (mask & inb)
        if (pm[b * NN + i] > 0) {
            float x = pim[(b * 4 + 0) * NN + i];
            float y = pim[(b * 4 + 1) * NN + i];
            float z = pim[(b * 4 + 2) * NN + i];
            int pos = atomicAdd(&counters[b], 1) + 1;
            cand[b * NN + pos] = make_float4(x, y, z, __int_as_float(i));

            int ix = (int)floorf((x - 0.0f)  / 0.16f);
            int iy = (int)floorf((y + 40.0f) / 0.16f);
            if (ix >= 0 && ix < NXv && iy >= 0 && iy < NYv &&
                z >= -3.0f && z < 1.0f) {
                int vox = iy * NXv + ix;
                nxt[b * N2 + i] = atomicExch(&head[b * NVOXv + vox], i);
            }
        }
    }
}

// ---------------------------------------------------------------------------
// Kernel 2: far 3-NN + interpolate -> F rows [NN,2NN); chain far points.
// 16 lanes per far point; each lane covers 2 channels in the epilogue.
// ---------------------------------------------------------------------------
__global__ __launch_bounds__(256) void k_far(
    const float4* __restrict__ cand,
    const int*    __restrict__ counters,
    const float4* __restrict__ fcand,
    float*        __restrict__ F,     // (B,2N,C)
    int*          __restrict__ head,
    int*          __restrict__ nxt)
{
    int b  = blockIdx.y;
    int nf = counters[2 + b] + 1;
    int e0 = blockIdx.x * FPB;
    if (e0 >= nf) return;

    int tid = threadIdx.x;
    int sub = tid & (SPLIT - 1);
    int e   = e0 + (tid >> 4);
    if (e >= nf) return;                 // uniform within each 16-lane group

    float4 fp = fcand[b * NN + e];
    float x = fp.x, y = fp.y, z = fp.z;
    int vox = __float_as_int(fp.w);

    int nc = counters[b] + 1;
    const float4* cb = cand + b * NN;

    float d0 = __builtin_inff(), d1 = __builtin_inff(), d2 = __builtin_inff();
    int   i0 = 0, i1 = 0, i2 = 0;

    int k = sub;
    for (; k + 48 < nc; k += 64) {
        float4 pa = cb[k];
        float4 pb = cb[k + 16];
        float4 pc = cb[k + 32];
        float4 pd = cb[k + 48];
        float dxa = x - pa.x, dya = y - pa.y, dza = z - pa.z;
        float dxb = x - pb.x, dyb = y - pb.y, dzb = z - pb.z;
        float dxc = x - pc.x, dyc = y - pc.y, dzc = z - pc.z;
        float dxd = x - pd.x, dyd = y - pd.y, dzd = z - pd.z;
        float da = dxa * dxa + dya * dya + dza * dza;
        float db = dxb * dxb + dyb * dyb + dzb * dzb;
        float dc = dxc * dxc + dyc * dyc + dzc * dzc;
        float dd = dxd * dxd + dyd * dyd + dzd * dzd;
        int ia = __float_as_int(pa.w);
        int ib = __float_as_int(pb.w);
        int ic = __float_as_int(pc.w);
        int id = __float_as_int(pd.w);
        INSERT3(da, ia);
        INSERT3(db, ib);
        INSERT3(dc, ic);
        INSERT3(dd, id);
    }
    for (; k < nc; k += SPLIT) {
        float4 p = cb[k];
        float dx = x - p.x, dy = y - p.y, dz = z - p.z;
        float d  = dx * dx + dy * dy + dz * dz;
        int  ii  = __float_as_int(p.w);
        INSERT3(d, ii);
    }

    // butterfly merge across the 16-lane group
#pragma unroll
    for (int off = 1; off < SPLIT; off <<= 1) {
        float m0 = __shfl_xor(d0, off), m1 = __shfl_xor(d1, off), m2 = __shfl_xor(d2, off);
        int   g0 = __shfl_xor(i0, off), g1 = __shfl_xor(i1, off), g2 = __shfl_xor(i2, off);
        INSERT3(m0, g0);
        INSERT3(m1, g1);
        INSERT3(m2, g2);
    }

    float r0 = 1.0f / (d0 + 1e-8f);
    float r1 = 1.0f / (d1 + 1e-8f);
    float r2 = 1.0f / (d2 + 1e-8f);
    float s  = r0 + r1 + r2;
    float w0 = r0 / s, w1 = r1 / s, w2 = r2 / s;

    // gather near features (rows < NN of F), write interp row NN+e (2 ch/lane)
    const float* fb = F + ((size_t)b * N2 << 5);
    float va = w0 * fb[((size_t)i0 << 5) + sub] +
               w1 * fb[((size_t)i1 << 5) + sub] +
               w2 * fb[((size_t)i2 << 5) + sub];
    float vb = w0 * fb[((size_t)i0 << 5) + sub + 16] +
               w1 * fb[((size_t)i1 << 5) + sub + 16] +
               w2 * fb[((size_t)i2 << 5) + sub + 16];
    size_t row = ((size_t)b * N2 + NN + e) << 5;
    F[row + sub]      = va;
    F[row + sub + 16] = vb;

    if (sub == 0)
        nxt[b * N2 + NN + e] = atomicExch(&head[b * NVOXv + vox], NN + e);
}

// ---------------------------------------------------------------------------
// Kernel 3: per-voxel chain walk -> mean -> transposed out (B,C,NY,NX)
// 64 voxels per block; 4 threads per voxel, 8 channels each.
// ---------------------------------------------------------------------------
__global__ __launch_bounds__(256) void k_final(
    const float* __restrict__ F,     // (B,2N,C)
    const int*   __restrict__ head,  // (B,NVOX)
    const int*   __restrict__ nxt,   // (B,2N)
    float*       __restrict__ out)   // (B,C,NVOX)
{
    __shared__ float tile[CC][64 + 1];
    int b  = blockIdx.y;
    int v0 = blockIdx.x * 64;
    int t  = threadIdx.x;

    int vl = t >> 2, cq = (t & 3) * 8;       // 4 threads per voxel, 8 ch each
    int v  = v0 + vl;
    float acc[8] = {0, 0, 0, 0, 0, 0, 0, 0};
    if (v < NVOXv) {
        int p = head[b * NVOXv + v];
        int n = 0;
        while (p >= 0) {
            const float* f = F + (((size_t)b * N2 + p) << 5) + cq;
            float4 a0 = *(const float4*)f;
            float4 a1 = *(const float4*)(f + 4);
            acc[0] += a0.x; acc[1] += a0.y; acc[2] += a0.z; acc[3] += a0.w;
            acc[4] += a1.x; acc[5] += a1.y; acc[6] += a1.z; acc[7] += a1.w;
            ++n;
            p = nxt[b * N2 + p];
        }
        if (n > 1) {
            float cf = (float)n;
#pragma unroll
            for (int u = 0; u < 8; ++u) acc[u] /= cf;
        }
    }
#pragma unroll
    for (int u = 0; u < 8; ++u) tile[cq + u][vl] = acc[u];
    __syncthreads();

    int c = t >> 3, vb = (t & 7) * 8;        // 8 threads per channel, 8 v each
    if (v0 + vb < NVOXv) {
        float* o = out + (size_t)b * CC * NVOXv + (size_t)c * NVOXv + v0 + vb;
        *(float4*)(o)     = make_float4(tile[c][vb + 0], tile[c][vb + 1],
                                        tile[c][vb + 2], tile[c][vb + 3]);
        *(float4*)(o + 4) = make_float4(tile[c][vb + 4], tile[c][vb + 5],
                                        tile[c][vb + 6], tile[c][vb + 7]);
    }
}

// ---------------------------------------------------------------------------
extern "C" void kernel_launch(void* const* d_in, const int* in_sizes, int n_in,
                              void* d_out, int out_size, void* d_ws, size_t ws_size,
                              hipStream_t stream)
{
    const float* fv   = (const float*)d_in[0];
    const float* pim  = (const float*)d_in[1];
    const float* pimf = (const float*)d_in[2];
    const int*   pm   = (const int*)d_in[3];
    const int*   pmf  = (const int*)d_in[4];
    float* out = (float*)d_out;

    const size_t headB = (size_t)BB * NVOXv * sizeof(int);     // 1,760,000
    const size_t nxtB  = (size_t)BB * N2 * sizeof(int);        //   131,072
    const size_t candB = (size_t)BB * NN * sizeof(float4);     //   524,288
    const size_t FB    = (size_t)BB * N2 * CC * sizeof(float); // 4,194,304

    char* ws = (char*)d_ws;
    int* counters = (int*)ws;             // [ccnt0, ccnt1, fcnt0, fcnt1], init -1
    size_t off = 256;
    int*    head  = (int*)(ws + off);   off += headB;
    int*    nxt   = (int*)(ws + off);   off += nxtB;
    float4* cand  = (float4*)(ws + off); off += candB;
    float4* fcand = (float4*)(ws + off); off += candB;
    float*  F     = (float*)(ws + off);  off += FB;
    (void)ws_size;

    // ONE fill covers counters (-1) and head (-1)
    hipMemsetAsync(d_ws, 0xFF, 256 + headB, stream);

    dim3 blk(256);
    dim3 g1(NN / 64, BB);
    k_prep<<<g1, blk, 0, stream>>>(fv, pim, pimf, pm, pmf,
                                   F, head, nxt, cand, counters, fcand);

    dim3 g2(NN / FPB, BB);
    k_far<<<g2, blk, 0, stream>>>(cand, counters, fcand, F, head, nxt);

    dim3 g3((NVOXv + 63) / 64, BB);
    k_final<<<g3, blk, 0, stream>>>(F, head, nxt, out);
}

// Round 7
// 124.929 us; speedup vs baseline: 1.1190x; 1.1190x over previous
//
#include <hip/hip_runtime.h>

// Problem constants (fixed shapes from setup_inputs / PROJECT_CFG)
#define BB   2
#define CC   32
#define NN   8192               // H*W points per batch
#define N2   (2 * NN)           // near rows [0,NN) + far rows [NN,2NN) in F
#define NXv  440
#define NYv  500
#define NVOXv (NXv * NYv)       // 220000

#define SPLIT 64                // lanes per far point (full wave)
#define FPB   4                 // far points per 256-thread block

// Branchless top-3 insert: 3 v_cmp + 10 v_cndmask, shallow dep chain.
#define INS3(dd, jj) do {                                          \
    bool c0 = (dd) < d0, c1 = (dd) < d1, c2 = (dd) < d2;           \
    float nd2 = c1 ? d1 : (c2 ? (dd) : d2);                        \
    int   ni2 = c1 ? i1 : (c2 ? (jj) : i2);                        \
    float nd1 = c0 ? d0 : (c1 ? (dd) : d1);                        \
    int   ni1 = c0 ? i0 : (c1 ? (jj) : i1);                        \
    float nd0 = c0 ? (dd) : d0;                                    \
    int   ni0 = c0 ? (jj) : i0;                                    \
    d0 = nd0; d1 = nd1; d2 = nd2; i0 = ni0; i1 = ni1; i2 = ni2;    \
} while (0)

// ---------------------------------------------------------------------------
// Fused: fv (B,C,N) -> F rows [0,NN) as (B,N,C)  +  compact near/far + chain.
// Counters start at -1 (0xFF memset): pos = atomicAdd(c,1)+1, count = c+1.
// ---------------------------------------------------------------------------
__global__ __launch_bounds__(256) void k_prep(
    const float* __restrict__ fv,    // (B,C,N)
    const float* __restrict__ pim,   // (B,4,N)
    const float* __restrict__ pimf,  // (B,4,N)
    const int*   __restrict__ pm,    // (B,N)
    const int*   __restrict__ pmf,   // (B,N)
    float*       __restrict__ F,     // (B,2N,C)
    int*         __restrict__ head,  // (B,NVOX), init -1
    int*         __restrict__ nxt,   // (B,2N)
    float4*      __restrict__ cand,  // (B,N)
    int*         __restrict__ counters, // [ccnt0,ccnt1,fcnt0,fcnt1], init -1
    float4*      __restrict__ fcand) // (B,N)
{
    __shared__ float tile[CC][64 + 1];
    int b  = blockIdx.y;
    int i0 = blockIdx.x * 64;
    int t  = threadIdx.x;

    // ---- transpose 64 points of fv into F rows [0,NN) ----
    const float* f = fv + (size_t)b * CC * NN;
    int il = t & 63, cb = t >> 6;            // cb 0..3
#pragma unroll
    for (int p = 0; p < 8; ++p) {
        int c = cb + p * 4;
        tile[c][il] = f[(size_t)c * NN + i0 + il];
    }
    __syncthreads();
    float* o = F + ((size_t)b * N2 + i0) * CC;
    int c2 = t & 31, ib = t >> 5;            // ib 0..7
#pragma unroll
    for (int p = 0; p < 8; ++p) {
        int il2 = ib + p * 8;
        o[(size_t)il2 * CC + c2] = tile[c2][il2];
    }

    // ---- wave 0: compact + chain the same 64 points ----
    if (t < 64) {
        int i = i0 + t;

        // far point: compact (pmf>0 && in-bounds); store vox in .w
        {
            float x = pimf[(b * 4 + 0) * NN + i];
            float y = pimf[(b * 4 + 1) * NN + i];
            float z = pimf[(b * 4 + 2) * NN + i];
            if (pmf[b * NN + i] > 0) {
                int ix = (int)floorf((x - 0.0f)  / 0.16f);
                int iy = (int)floorf((y + 40.0f) / 0.16f);
                if (ix >= 0 && ix < NXv && iy >= 0 && iy < NYv &&
                    z >= -3.0f && z < 1.0f) {
                    int vox = iy * NXv + ix;
                    int pos = atomicAdd(&counters[2 + b], 1) + 1;
                    fcand[b * NN + pos] = make_float4(x, y, z, __int_as_float(vox));
                }
            }
        }

        // near point: candidate list (mask only) + chain (mask & inb)
        if (pm[b * NN + i] > 0) {
            float x = pim[(b * 4 + 0) * NN + i];
            float y = pim[(b * 4 + 1) * NN + i];
            float z = pim[(b * 4 + 2) * NN + i];
            int pos = atomicAdd(&counters[b], 1) + 1;
            cand[b * NN + pos] = make_float4(x, y, z, __int_as_float(i));

            int ix = (int)floorf((x - 0.0f)  / 0.16f);
            int iy = (int)floorf((y + 40.0f) / 0.16f);
            if (ix >= 0 && ix < NXv && iy >= 0 && iy < NYv &&
                z >= -3.0f && z < 1.0f) {
                int vox = iy * NXv + ix;
                nxt[b * N2 + i] = atomicExch(&head[b * NVOXv + vox], i);
            }
        }
    }
}

// ---------------------------------------------------------------------------
// Kernel 2: far 3-NN + interpolate -> F rows [NN,2NN); chain far points.
// One full wave (64 lanes) per far point -> nf waves/batch in flight.
// ---------------------------------------------------------------------------
__global__ __launch_bounds__(256) void k_far(
    const float4* __restrict__ cand,
    const int*    __restrict__ counters,
    const float4* __restrict__ fcand,
    float*        __restrict__ F,     // (B,2N,C)
    int*          __restrict__ head,
    int*          __restrict__ nxt)
{
    int b  = blockIdx.y;
    int nf = counters[2 + b] + 1;
    int e0 = blockIdx.x * FPB;
    if (e0 >= nf) return;

    int tid = threadIdx.x;
    int sub = tid & (SPLIT - 1);          // lane within wave
    int e   = e0 + (tid >> 6);            // wave's far point
    if (e >= nf) return;                  // wave-uniform

    float4 fp = fcand[b * NN + e];
    float x = fp.x, y = fp.y, z = fp.z;
    int vox = __float_as_int(fp.w);

    int nc = counters[b] + 1;
    const float4* cb = cand + b * NN;

    float d0 = __builtin_inff(), d1 = __builtin_inff(), d2 = __builtin_inff();
    int   i0 = 0, i1 = 0, i2 = 0;

    int k = sub;
    for (; k + 192 < nc; k += 256) {
        float4 pa = cb[k];
        float4 pb = cb[k + 64];
        float4 pc = cb[k + 128];
        float4 pd = cb[k + 192];
        float dxa = x - pa.x, dya = y - pa.y, dza = z - pa.z;
        float dxb = x - pb.x, dyb = y - pb.y, dzb = z - pb.z;
        float dxc = x - pc.x, dyc = y - pc.y, dzc = z - pc.z;
        float dxd = x - pd.x, dyd = y - pd.y, dzd = z - pd.z;
        float da = dxa * dxa + dya * dya + dza * dza;
        float db = dxb * dxb + dyb * dyb + dzb * dzb;
        float dc = dxc * dxc + dyc * dyc + dzc * dzc;
        float dd = dxd * dxd + dyd * dyd + dzd * dzd;
        int ia = __float_as_int(pa.w);
        int ib = __float_as_int(pb.w);
        int ic = __float_as_int(pc.w);
        int id = __float_as_int(pd.w);
        INS3(da, ia);
        INS3(db, ib);
        INS3(dc, ic);
        INS3(dd, id);
    }
    for (; k < nc; k += SPLIT) {
        float4 p = cb[k];
        float dx = x - p.x, dy = y - p.y, dz = z - p.z;
        float d  = dx * dx + dy * dy + dz * dz;
        int  ii  = __float_as_int(p.w);
        INS3(d, ii);
    }

    // butterfly merge across all 64 lanes
#pragma unroll
    for (int off = 1; off < SPLIT; off <<= 1) {
        float m0 = __shfl_xor(d0, off), m1 = __shfl_xor(d1, off), m2 = __shfl_xor(d2, off);
        int   g0 = __shfl_xor(i0, off), g1 = __shfl_xor(i1, off), g2 = __shfl_xor(i2, off);
        INS3(m0, g0);
        INS3(m1, g1);
        INS3(m2, g2);
    }

    float r0 = 1.0f / (d0 + 1e-8f);
    float r1 = 1.0f / (d1 + 1e-8f);
    float r2 = 1.0f / (d2 + 1e-8f);
    float s  = r0 + r1 + r2;
    float w0 = r0 / s, w1 = r1 / s, w2 = r2 / s;

    // gather near features (rows < NN of F), write interp row NN+e
    if (sub < CC) {
        const float* fb = F + ((size_t)b * N2 << 5);
        float v = w0 * fb[((size_t)i0 << 5) + sub] +
                  w1 * fb[((size_t)i1 << 5) + sub] +
                  w2 * fb[((size_t)i2 << 5) + sub];
        F[(((size_t)b * N2 + NN + e) << 5) + sub] = v;
    }

    if (sub == 0)
        nxt[b * N2 + NN + e] = atomicExch(&head[b * NVOXv + vox], NN + e);
}

// ---------------------------------------------------------------------------
// Kernel 3: per-voxel chain walk -> mean -> transposed out (B,C,NY,NX)
// 64 voxels per block; 4 threads per voxel, 8 channels each.
// ---------------------------------------------------------------------------
__global__ __launch_bounds__(256) void k_final(
    const float* __restrict__ F,     // (B,2N,C)
    const int*   __restrict__ head,  // (B,NVOX)
    const int*   __restrict__ nxt,   // (B,2N)
    float*       __restrict__ out)   // (B,C,NVOX)
{
    __shared__ float tile[CC][64 + 1];
    int b  = blockIdx.y;
    int v0 = blockIdx.x * 64;
    int t  = threadIdx.x;

    int vl = t >> 2, cq = (t & 3) * 8;       // 4 threads per voxel, 8 ch each
    int v  = v0 + vl;
    float acc[8] = {0, 0, 0, 0, 0, 0, 0, 0};
    if (v < NVOXv) {
        int p = head[b * NVOXv + v];
        int n = 0;
        while (p >= 0) {
            const float* f = F + (((size_t)b * N2 + p) << 5) + cq;
            float4 a0 = *(const float4*)f;
            float4 a1 = *(const float4*)(f + 4);
            acc[0] += a0.x; acc[1] += a0.y; acc[2] += a0.z; acc[3] += a0.w;
            acc[4] += a1.x; acc[5] += a1.y; acc[6] += a1.z; acc[7] += a1.w;
            ++n;
            p = nxt[b * N2 + p];
        }
        if (n > 1) {
            float cf = (float)n;
#pragma unroll
            for (int u = 0; u < 8; ++u) acc[u] /= cf;
        }
    }
#pragma unroll
    for (int u = 0; u < 8; ++u) tile[cq + u][vl] = acc[u];
    __syncthreads();

    int c = t >> 3, vb = (t & 7) * 8;        // 8 threads per channel, 8 v each
    if (v0 + vb < NVOXv) {
        float* o = out + (size_t)b * CC * NVOXv + (size_t)c * NVOXv + v0 + vb;
        *(float4*)(o)     = make_float4(tile[c][vb + 0], tile[c][vb + 1],
                                        tile[c][vb + 2], tile[c][vb + 3]);
        *(float4*)(o + 4) = make_float4(tile[c][vb + 4], tile[c][vb + 5],
                                        tile[c][vb + 6], tile[c][vb + 7]);
    }
}

// ---------------------------------------------------------------------------
extern "C" void kernel_launch(void* const* d_in, const int* in_sizes, int n_in,
                              void* d_out, int out_size, void* d_ws, size_t ws_size,
                              hipStream_t stream)
{
    const float* fv   = (const float*)d_in[0];
    const float* pim  = (const float*)d_in[1];
    const float* pimf = (const float*)d_in[2];
    const int*   pm   = (const int*)d_in[3];
    const int*   pmf  = (const int*)d_in[4];
    float* out = (float*)d_out;

    const size_t headB = (size_t)BB * NVOXv * sizeof(int);     // 1,760,000
    const size_t nxtB  = (size_t)BB * N2 * sizeof(int);        //   131,072
    const size_t candB = (size_t)BB * NN * sizeof(float4);     //   524,288
    const size_t FB    = (size_t)BB * N2 * CC * sizeof(float); // 4,194,304

    char* ws = (char*)d_ws;
    int* counters = (int*)ws;             // [ccnt0, ccnt1, fcnt0, fcnt1], init -1
    size_t off = 256;
    int*    head  = (int*)(ws + off);   off += headB;
    int*    nxt   = (int*)(ws + off);   off += nxtB;
    float4* cand  = (float4*)(ws + off); off += candB;
    float4* fcand = (float4*)(ws + off); off += candB;
    float*  F     = (float*)(ws + off);  off += FB;
    (void)ws_size;

    // ONE fill covers counters (-1) and head (-1)
    hipMemsetAsync(d_ws, 0xFF, 256 + headB, stream);

    dim3 blk(256);
    dim3 g1(NN / 64, BB);
    k_prep<<<g1, blk, 0, stream>>>(fv, pim, pimf, pm, pmf,
                                   F, head, nxt, cand, counters, fcand);

    dim3 g2(NN / FPB, BB);
    k_far<<<g2, blk, 0, stream>>>(cand, counters, fcand, F, head, nxt);

    dim3 g3((NVOXv + 63) / 64, BB);
    k_final<<<g3, blk, 0, stream>>>(F, head, nxt, out);
}